// Round 3
// baseline (335.984 us; speedup 1.0000x reference)
//
#include <hip/hip_runtime.h>
#include <math.h>

// Problem constants: B=4,S=4096,IN=2048,E=16,D=128,A=128,R=4
#define NTOK   16384
#define INDIM  2048
#define NROWS  20      // 16 Wv rows + 4 mlp_w1 rows
#define CHUNK  256     // K-chunk (floats): 1 KB per row, 8 chunks
#define NCH    8

// workspace (float) layout
#define WS_PKT  0      // PKt[e2][r][e]  : 16*4*16 = 1024
#define WS_D1K  1024   // [e2][e] 256
#define WS_GQK  1280   // [e2][e] 256
#define WS_BQK  1536   // [e2][e] 256
#define WS_SCAL 1792   // m0,q0,mW[4],q1[4],Q2[16] = 26
#define WS_TOT  1818

#define SIM_SCALE 0.08838834764831845f  // 1/sqrt(128)

// LDS float offsets inside hr_main's 40960-byte block
#define LBUF1   5120                 // second weight buffer
#define LRED2_STRIDE 324             // per-token stride of scatter buffer (16B-aligned, odd/32 banks)
#define LRED    5440                 // red[16][20] after K-loop (aliased over wbuf)

// ---------------------------------------------------------------------------
// async 16B global -> LDS copy (global_load_lds_dwordx4); LDS dest is
// wave-uniform base + lane*16, so pass the row base; gptr is per-lane.
// ---------------------------------------------------------------------------
__device__ __forceinline__ void async16(const float* g, float* l) {
    __builtin_amdgcn_global_load_lds(
        (const __attribute__((address_space(1))) void*)g,
        (__attribute__((address_space(3))) void*)l, 16, 0, 0);
}

// stage this wave's 5 weight rows (r = wave, wave+4, ..., wave+16) for one
// K-chunk into ldsbase[r*CHUNK ...]; j<4 -> wv rows (compile-time), j==4 -> w1.
__device__ __forceinline__ void stage_rows(const float* __restrict__ wv,
                                           const float* __restrict__ w1,
                                           float* ldsbase, int wave, int lane,
                                           int goff) {
    const int l4 = lane << 2;
    #pragma unroll
    for (int j = 0; j < 5; ++j) {
        const int r = wave + (j << 2);
        const float* src = (j < 4) ? (wv + (r << 11)) : (w1 + ((r - 16) << 11));
        async16(src + goff + l4, ldsbase + r * CHUNK + l4);
    }
}

__device__ __forceinline__ void load_h(float4* hr, const float* hb, int c) {
    const float* p = hb + (c << 8);
    hr[0] = *(const float4*)(p);
    hr[1] = *(const float4*)(p + INDIM);
    hr[2] = *(const float4*)(p + 2 * INDIM);
    hr[3] = *(const float4*)(p + 3 * INDIM);
}

__device__ __forceinline__ void compute_chunk(float acc[NROWS][4],
                                              const float* wb,
                                              const float4 h[4]) {
    #pragma unroll
    for (int w = 0; w < NROWS; ++w) {
        float4 wf = *(const float4*)(wb + (w << 8));   // ds_read_b128, conflict-free
        #pragma unroll
        for (int t = 0; t < 4; ++t) {
            acc[w][t] = fmaf(h[t].x, wf.x,
                        fmaf(h[t].y, wf.y,
                        fmaf(h[t].z, wf.z,
                        fmaf(h[t].w, wf.w, acc[w][t]))));
        }
    }
}

// ---------------------------------------------------------------------------
// Precompute kernel: 17 blocks x 256 threads (unchanged, known-good).
// ---------------------------------------------------------------------------
__global__ __launch_bounds__(256) void hr_pre2(
    const float* __restrict__ ee, const float* __restrict__ gam,
    const float* __restrict__ bta, const float* __restrict__ w2,
    const float* __restrict__ b2, const float* __restrict__ wq,
    const float* __restrict__ wk, float* __restrict__ ws)
{
    const int tid  = threadIdx.x;
    const int bx   = blockIdx.x;
    const int lane = tid & 63;
    const int wave = tid >> 6;

    if (bx == 16) {
        __shared__ float sacc[26];
        if (tid < 26) sacc[tid] = 0.f;
        __syncthreads();
        float pa[26];
        #pragma unroll
        for (int j = 0; j < 26; ++j) pa[j] = 0.f;
        for (int i = tid; i < 2048; i += 256) {
            float b = b2[i];
            float4 w4 = *(const float4*)(w2 + i * 4);
            float wr[4] = {w4.x, w4.y, w4.z, w4.w};
            pa[0] += b;
            pa[1] += b * b;
            #pragma unroll
            for (int r = 0; r < 4; ++r) {
                pa[2 + r] += wr[r];
                pa[6 + r] += b * wr[r];
                #pragma unroll
                for (int r2 = 0; r2 < 4; ++r2) pa[10 + r * 4 + r2] += wr[r] * wr[r2];
            }
        }
        #pragma unroll
        for (int j = 0; j < 26; ++j) {
            float v = pa[j];
            v += __shfl_xor(v, 32); v += __shfl_xor(v, 16); v += __shfl_xor(v, 8);
            v += __shfl_xor(v, 4);  v += __shfl_xor(v, 2);  v += __shfl_xor(v, 1);
            if (lane == 0) atomicAdd(&sacc[j], v);
        }
        __syncthreads();
        if (tid < 26) ws[WS_SCAL + tid] = sacc[tid] * (1.f / 2048.f);
        return;
    }

    const int e2 = bx;
    __shared__ float sge[128];
    __shared__ float sK[128];
    __shared__ float sWqK[128];
    __shared__ float sred[8];

    float v8[8];
    float s = 0.f;
    #pragma unroll
    for (int j = 0; j < 8; ++j) { v8[j] = ee[tid + j * 256]; s += v8[j]; }
    s += __shfl_xor(s, 32); s += __shfl_xor(s, 16); s += __shfl_xor(s, 8);
    s += __shfl_xor(s, 4);  s += __shfl_xor(s, 2);  s += __shfl_xor(s, 1);
    if (lane == 0) sred[wave] = s;
    __syncthreads();
    const float mu = (sred[0] + sred[1] + sred[2] + sred[3]) * (1.f / 2048.f);
    float q = 0.f;
    #pragma unroll
    for (int j = 0; j < 8; ++j) { float d = v8[j] - mu; q += d * d; }
    q += __shfl_xor(q, 32); q += __shfl_xor(q, 16); q += __shfl_xor(q, 8);
    q += __shfl_xor(q, 4);  q += __shfl_xor(q, 2);  q += __shfl_xor(q, 1);
    if (lane == 0) sred[4 + wave] = q;
    __syncthreads();
    const float rsq = rsqrtf((sred[4] + sred[5] + sred[6] + sred[7]) * (1.f / 2048.f) + 1e-5f);

    if (tid < 128) {
        int idx = (e2 << 7) + tid;
        sge[tid] = (ee[idx] - mu) * rsq * gam[idx] + bta[idx];
    }
    __syncthreads();

    {
        int a = tid >> 1, half = tid & 1;
        const float* wr = wk + (a << 7) + (half << 6);
        const float* gg = sge + (half << 6);
        float acc = 0.f;
        #pragma unroll 8
        for (int j = 0; j < 64; ++j) acc = fmaf(gg[j], wr[j], acc);
        acc += __shfl_xor(acc, 1);
        if (half == 0) sK[a] = acc;
    }
    __syncthreads();

    {
        int d = tid >> 1, half = tid & 1;
        float acc = 0.f;
        #pragma unroll 8
        for (int j = 0; j < 64; ++j) {
            int a = (half << 6) + j;
            acc = fmaf(wq[(a << 7) + d], sK[a], acc);
        }
        acc += __shfl_xor(acc, 1);
        if (half == 0) sWqK[d] = acc;
    }
    __syncthreads();

    {
        int o = tid >> 2, qd = tid & 3;
        int r = o >> 4, e = o & 15;
        float acc = 0.f;
        #pragma unroll 8
        for (int j = 0; j < 32; ++j) {
            int d  = (qd << 5) + j;
            int ed = (e << 7) + d;
            acc = fmaf(w2[ed * 4 + r] * gam[ed], sWqK[d], acc);
        }
        acc += __shfl_xor(acc, 1);
        acc += __shfl_xor(acc, 2);
        if (qd == 0) ws[WS_PKT + (e2 << 6) + (r << 4) + e] = acc;
    }

    if (tid < 192) {
        int kind = tid >> 6;
        int e    = (tid >> 2) & 15;
        int qd   = tid & 3;
        float acc = 0.f;
        #pragma unroll 8
        for (int j = 0; j < 32; ++j) {
            int d  = (qd << 5) + j;
            int ed = (e << 7) + d;
            float w = sWqK[d];
            float t = (kind == 0) ? b2[ed] * gam[ed]
                    : (kind == 1) ? gam[ed]
                                  : bta[ed];
            acc = fmaf(t, w, acc);
        }
        acc += __shfl_xor(acc, 1);
        acc += __shfl_xor(acc, 2);
        if (qd == 0) ws[WS_D1K + (kind << 8) + (e2 << 4) + e] = acc;
    }
}

// ---------------------------------------------------------------------------
// Main kernel v3: 1024 blocks x 256 thr, 16 tokens/block (4/wave).
// Double-buffered LDS weight tiles staged with global_load_lds (width 16);
// hidden double-buffered in registers; cheap 2-level-butterfly + LDS
// scatter/gather reduction; routing tail per (token, expert) thread.
// ---------------------------------------------------------------------------
__global__ __launch_bounds__(256, 3) void hr_main(
    const float* __restrict__ hidden, const float* __restrict__ wv,
    const float* __restrict__ wvb, const float* __restrict__ w1,
    const float* __restrict__ b1, const float* __restrict__ tab,
    float* __restrict__ out)
{
    __shared__ float lds[10240];   // 40960 B: wbuf[2][20][256]; aliased by epilogue

    const int tid  = threadIdx.x;
    const int wave = tid >> 6;
    const int lane = tid & 63;
    const int tok0 = (blockIdx.x << 4) + (wave << 2);
    const float* hb = hidden + (size_t)tok0 * INDIM + (lane << 2);

    float acc[NROWS][4];
    #pragma unroll
    for (int w = 0; w < NROWS; ++w) {
        acc[w][0] = 0.f; acc[w][1] = 0.f; acc[w][2] = 0.f; acc[w][3] = 0.f;
    }

    float4 ha[4], hob[4];
    stage_rows(wv, w1, lds, wave, lane, 0);   // chunk 0 -> buf0
    load_h(ha, hb, 0);
    __syncthreads();                           // staging 0 complete (vmcnt drain)

    for (int cc = 0; cc < 4; ++cc) {
        const int c1 = 2 * cc + 1;
        // prefetch odd chunk into buf1 while computing even from buf0
        stage_rows(wv, w1, lds + LBUF1, wave, lane, c1 << 8);
        load_h(hob, hb, c1);
        compute_chunk(acc, &lds[lane << 2], ha);
        __syncthreads();
        // prefetch next even chunk into buf0 while computing odd from buf1
        if (cc != 3) {
            stage_rows(wv, w1, lds, wave, lane, (c1 + 1) << 8);
            load_h(ha, hb, c1 + 1);
        }
        compute_chunk(acc, &lds[LBUF1 + (lane << 2)], hob);
        __syncthreads();
    }

    // ---- reduction: 2 butterfly levels -> 16 partials per (w,t) ----
    #pragma unroll
    for (int w = 0; w < NROWS; ++w) {
        #pragma unroll
        for (int t = 0; t < 4; ++t) {
            float v = acc[w][t];
            v += __shfl_xor(v, 32);
            v += __shfl_xor(v, 16);
            acc[w][t] = v;     // lane l holds partial for i = l&15
        }
    }
    // scatter: quarter q = lane>>4 writes rows 5q..5q+4 (w/5 is compile-time)
    {
        const int q = lane >> 4, i = lane & 15;
        #pragma unroll
        for (int w = 0; w < NROWS; ++w) {
            if (q == w / 5) {
                #pragma unroll
                for (int t = 0; t < 4; ++t)
                    lds[((wave << 2) + t) * LRED2_STRIDE + (w << 4) + i] = acc[w][t];
            }
        }
    }
    __syncthreads();

    // gather: 320 (tok,w) pairs, sum 16 partials each -> red[tok][w]
    #pragma unroll
    for (int pp = 0; pp < 2; ++pp) {
        const int p = tid + pp * 256;
        if (p < 320) {
            const int w = p >> 4, tok = p & 15;
            const float4* rp = (const float4*)&lds[tok * LRED2_STRIDE + (w << 4)];
            float4 r0 = rp[0], r1 = rp[1], r2 = rp[2], r3 = rp[3];
            float s = (r0.x + r0.y + r0.z + r0.w) + (r1.x + r1.y + r1.z + r1.w)
                    + (r2.x + r2.y + r2.z + r2.w) + (r3.x + r3.y + r3.z + r3.w);
            lds[LRED + tok * 20 + w] = s;
        }
    }
    __syncthreads();

    // ---- tail: 16 threads per token, thread = (tok, e); tab read from L2 ----
    const int tok = tid >> 4;
    const int e   = tid & 15;

    float ig[16];
    #pragma unroll
    for (int j = 0; j < 16; ++j) ig[j] = lds[LRED + tok * 20 + j] + wvb[j];
    float h[4];
    #pragma unroll
    for (int r = 0; r < 4; ++r) h[r] = fmaxf(lds[LRED + tok * 20 + 16 + r] + b1[r], 0.f);

    float muT = tab[WS_SCAL + 0];
    float e2m = tab[WS_SCAL + 1];
    #pragma unroll
    for (int r = 0; r < 4; ++r) {
        muT = fmaf(h[r], tab[WS_SCAL + 2 + r], muT);
        e2m = fmaf(2.f * h[r], tab[WS_SCAL + 6 + r], e2m);
        #pragma unroll
        for (int r2 = 0; r2 < 4; ++r2)
            e2m = fmaf(h[r] * h[r2], tab[WS_SCAL + 10 + r * 4 + r2], e2m);
    }
    const float var = e2m - muT * muT;
    const float rsq = rsqrtf(var + 1e-5f);

    float sv[16];
    #pragma unroll
    for (int e2 = 0; e2 < 16; ++e2) {
        float s = tab[WS_D1K + (e2 << 4) + e];
        s = fmaf(h[0], tab[(e2 << 6) + e], s);
        s = fmaf(h[1], tab[(e2 << 6) + 16 + e], s);
        s = fmaf(h[2], tab[(e2 << 6) + 32 + e], s);
        s = fmaf(h[3], tab[(e2 << 6) + 48 + e], s);
        s = fmaf(-muT, tab[WS_GQK + (e2 << 4) + e], s);
        sv[e2] = (rsq * s + tab[WS_BQK + (e2 << 4) + e]) * SIM_SCALE;
    }
    float mx = sv[0];
    #pragma unroll
    for (int e2 = 1; e2 < 16; ++e2) mx = fmaxf(mx, sv[e2]);
    float den = 0.f, gate = 0.f;
    #pragma unroll
    for (int e2 = 0; e2 < 16; ++e2) {
        float p = __expf(sv[e2] - mx);
        den += p;
        gate = fmaf(p, ig[e2], gate);
    }
    gate /= den;

    float gm = gate;
    gm = fmaxf(gm, __shfl_xor(gm, 1));
    gm = fmaxf(gm, __shfl_xor(gm, 2));
    gm = fmaxf(gm, __shfl_xor(gm, 4));
    gm = fmaxf(gm, __shfl_xor(gm, 8));
    float ex = __expf(gate - gm);
    float es = ex;
    es += __shfl_xor(es, 1);
    es += __shfl_xor(es, 2);
    es += __shfl_xor(es, 4);
    es += __shfl_xor(es, 8);
    const float rw = ex / es;

    float v1 = rw; int i1 = e;
    #pragma unroll
    for (int m = 1; m <= 8; m <<= 1) {
        float ov = __shfl_xor(v1, m);
        int   oi = __shfl_xor(i1, m);
        if (ov > v1 || (ov == v1 && oi < i1)) { v1 = ov; i1 = oi; }
    }
    float v2 = (e == i1) ? -INFINITY : rw; int i2 = e;
    #pragma unroll
    for (int m = 1; m <= 8; m <<= 1) {
        float ov = __shfl_xor(v2, m);
        int   oi = __shfl_xor(i2, m);
        if (ov > v2 || (ov == v2 && oi < i2)) { v2 = ov; i2 = oi; }
    }

    float oval = 0.f;
    if (e == i1 || e == i2) {
        float t = __expf((v2 - v1) * 10.f);
        oval = (e == i1) ? (1.f / (1.f + t)) : (t / (1.f + t));
    }
    out[(((size_t)blockIdx.x << 4) + tok) * 16 + e] = oval;
}

// ---------------------------------------------------------------------------
extern "C" void kernel_launch(void* const* d_in, const int* in_sizes, int n_in,
                              void* d_out, int out_size, void* d_ws, size_t ws_size,
                              hipStream_t stream)
{
    const float* hidden = (const float*)d_in[0];   // (4,4096,2048)
    const float* ee     = (const float*)d_in[1];   // (16,128)
    const float* gam    = (const float*)d_in[2];   // (16,128)
    const float* bta    = (const float*)d_in[3];   // (16,128)
    const float* wv     = (const float*)d_in[4];   // (16,2048)
    const float* wvb    = (const float*)d_in[5];   // (16,)
    const float* w1     = (const float*)d_in[6];   // (4,2048)
    const float* b1     = (const float*)d_in[7];   // (4,)
    const float* w2     = (const float*)d_in[8];   // (2048,4)
    const float* b2     = (const float*)d_in[9];   // (2048,)
    const float* wq     = (const float*)d_in[10];  // (128,128)
    const float* wk     = (const float*)d_in[11];  // (128,128)
    float* out = (float*)d_out;
    float* ws  = (float*)d_ws;

    hipLaunchKernelGGL(hr_pre2, dim3(17), dim3(256), 0, stream,
                       ee, gam, bta, w2, b2, wq, wk, ws);
    hipLaunchKernelGGL(hr_main, dim3(NTOK / 16), dim3(256), 0, stream,
                       hidden, wv, wvb, w1, b1, ws, out);
}

// Round 4
// 263.360 us; speedup vs baseline: 1.2758x; 1.2758x over previous
//
#include <hip/hip_runtime.h>
#include <math.h>

// Problem constants: B=4,S=4096,IN=2048,E=16,D=128,A=128,R=4
#define NTOK   16384
#define INDIM  2048
#define NROWS  20      // 16 Wv rows + 4 mlp_w1 rows
#define CHUNK  256     // K-chunk (floats): 1 KB per row, 8 chunks

// workspace (float) layout
#define WS_PKT  0      // PKt[e2][r][e]  : 16*4*16 = 1024
#define WS_D1K  1024   // [e2][e] 256
#define WS_GQK  1280   // [e2][e] 256
#define WS_BQK  1536   // [e2][e] 256
#define WS_SCAL 1792   // m0,q0,mW[4],q1[4],Q2[16] = 26
#define WS_TOT  1818

#define SIM_SCALE 0.08838834764831845f  // 1/sqrt(128)

// LDS float offsets inside hr_main's 40960-byte block
#define LBUF1   5120                 // second weight buffer
#define LRED2_STRIDE 324             // per-token stride of scatter buffer
#define LRED    5440                 // red[16][20] epilogue buffer (aliased)

// ---------------------------------------------------------------------------
// async 16B global -> LDS (global_load_lds_dwordx4). LDS dest is wave-uniform
// base (readfirstlane) + lane*16; global src is per-lane.
// ---------------------------------------------------------------------------
__device__ __forceinline__ void async16(const float* g, float* l) {
    __builtin_amdgcn_global_load_lds(
        (const __attribute__((address_space(1))) void*)g,
        (__attribute__((address_space(3))) void*)l, 16, 0, 0);
}

// stage this wave's 5 weight rows (r = wave, wave+4, ..., wave+16) for one
// K-chunk into ldsbase[r*CHUNK ...]
__device__ __forceinline__ void stage_rows(const float* __restrict__ wv,
                                           const float* __restrict__ w1,
                                           float* ldsbase, int wave, int lane,
                                           int goff) {
    const int l4 = lane << 2;
    #pragma unroll
    for (int j = 0; j < 5; ++j) {
        const int r = wave + (j << 2);
        const float* src = (j < 4) ? (wv + (r << 11)) : (w1 + ((r - 16) << 11));
        async16(src + goff + l4, ldsbase + r * CHUNK + l4);
    }
}

__device__ __forceinline__ void load_h(float4* hr, const float* hb, int c) {
    const float* p = hb + (c << 8);
    hr[0] = *(const float4*)(p);
    hr[1] = *(const float4*)(p + INDIM);
    hr[2] = *(const float4*)(p + 2 * INDIM);
    hr[3] = *(const float4*)(p + 3 * INDIM);
}

__device__ __forceinline__ void compute_chunk(float acc[NROWS][4],
                                              const float* wb,
                                              const float4 h[4]) {
    #pragma unroll
    for (int w = 0; w < NROWS; ++w) {
        float4 wf = *(const float4*)(wb + (w << 8));   // ds_read_b128
        #pragma unroll
        for (int t = 0; t < 4; ++t) {
            acc[w][t] = fmaf(h[t].x, wf.x,
                        fmaf(h[t].y, wf.y,
                        fmaf(h[t].z, wf.z,
                        fmaf(h[t].w, wf.w, acc[w][t]))));
        }
    }
}

// ---------------------------------------------------------------------------
// Precompute kernel: 17 blocks x 256 threads (unchanged, known-good).
// ---------------------------------------------------------------------------
__global__ __launch_bounds__(256) void hr_pre2(
    const float* __restrict__ ee, const float* __restrict__ gam,
    const float* __restrict__ bta, const float* __restrict__ w2,
    const float* __restrict__ b2, const float* __restrict__ wq,
    const float* __restrict__ wk, float* __restrict__ ws)
{
    const int tid  = threadIdx.x;
    const int bx   = blockIdx.x;
    const int lane = tid & 63;
    const int wave = tid >> 6;

    if (bx == 16) {
        __shared__ float sacc[26];
        if (tid < 26) sacc[tid] = 0.f;
        __syncthreads();
        float pa[26];
        #pragma unroll
        for (int j = 0; j < 26; ++j) pa[j] = 0.f;
        for (int i = tid; i < 2048; i += 256) {
            float b = b2[i];
            float4 w4 = *(const float4*)(w2 + i * 4);
            float wr[4] = {w4.x, w4.y, w4.z, w4.w};
            pa[0] += b;
            pa[1] += b * b;
            #pragma unroll
            for (int r = 0; r < 4; ++r) {
                pa[2 + r] += wr[r];
                pa[6 + r] += b * wr[r];
                #pragma unroll
                for (int r2 = 0; r2 < 4; ++r2) pa[10 + r * 4 + r2] += wr[r] * wr[r2];
            }
        }
        #pragma unroll
        for (int j = 0; j < 26; ++j) {
            float v = pa[j];
            v += __shfl_xor(v, 32); v += __shfl_xor(v, 16); v += __shfl_xor(v, 8);
            v += __shfl_xor(v, 4);  v += __shfl_xor(v, 2);  v += __shfl_xor(v, 1);
            if (lane == 0) atomicAdd(&sacc[j], v);
        }
        __syncthreads();
        if (tid < 26) ws[WS_SCAL + tid] = sacc[tid] * (1.f / 2048.f);
        return;
    }

    const int e2 = bx;
    __shared__ float sge[128];
    __shared__ float sK[128];
    __shared__ float sWqK[128];
    __shared__ float sred[8];

    float v8[8];
    float s = 0.f;
    #pragma unroll
    for (int j = 0; j < 8; ++j) { v8[j] = ee[tid + j * 256]; s += v8[j]; }
    s += __shfl_xor(s, 32); s += __shfl_xor(s, 16); s += __shfl_xor(s, 8);
    s += __shfl_xor(s, 4);  s += __shfl_xor(s, 2);  s += __shfl_xor(s, 1);
    if (lane == 0) sred[wave] = s;
    __syncthreads();
    const float mu = (sred[0] + sred[1] + sred[2] + sred[3]) * (1.f / 2048.f);
    float q = 0.f;
    #pragma unroll
    for (int j = 0; j < 8; ++j) { float d = v8[j] - mu; q += d * d; }
    q += __shfl_xor(q, 32); q += __shfl_xor(q, 16); q += __shfl_xor(q, 8);
    q += __shfl_xor(q, 4);  q += __shfl_xor(q, 2);  q += __shfl_xor(q, 1);
    if (lane == 0) sred[4 + wave] = q;
    __syncthreads();
    const float rsq = rsqrtf((sred[4] + sred[5] + sred[6] + sred[7]) * (1.f / 2048.f) + 1e-5f);

    if (tid < 128) {
        int idx = (e2 << 7) + tid;
        sge[tid] = (ee[idx] - mu) * rsq * gam[idx] + bta[idx];
    }
    __syncthreads();

    {
        int a = tid >> 1, half = tid & 1;
        const float* wr = wk + (a << 7) + (half << 6);
        const float* gg = sge + (half << 6);
        float acc = 0.f;
        #pragma unroll 8
        for (int j = 0; j < 64; ++j) acc = fmaf(gg[j], wr[j], acc);
        acc += __shfl_xor(acc, 1);
        if (half == 0) sK[a] = acc;
    }
    __syncthreads();

    {
        int d = tid >> 1, half = tid & 1;
        float acc = 0.f;
        #pragma unroll 8
        for (int j = 0; j < 64; ++j) {
            int a = (half << 6) + j;
            acc = fmaf(wq[(a << 7) + d], sK[a], acc);
        }
        acc += __shfl_xor(acc, 1);
        if (half == 0) sWqK[d] = acc;
    }
    __syncthreads();

    {
        int o = tid >> 2, qd = tid & 3;
        int r = o >> 4, e = o & 15;
        float acc = 0.f;
        #pragma unroll 8
        for (int j = 0; j < 32; ++j) {
            int d  = (qd << 5) + j;
            int ed = (e << 7) + d;
            acc = fmaf(w2[ed * 4 + r] * gam[ed], sWqK[d], acc);
        }
        acc += __shfl_xor(acc, 1);
        acc += __shfl_xor(acc, 2);
        if (qd == 0) ws[WS_PKT + (e2 << 6) + (r << 4) + e] = acc;
    }

    if (tid < 192) {
        int kind = tid >> 6;
        int e    = (tid >> 2) & 15;
        int qd   = tid & 3;
        float acc = 0.f;
        #pragma unroll 8
        for (int j = 0; j < 32; ++j) {
            int d  = (qd << 5) + j;
            int ed = (e << 7) + d;
            float w = sWqK[d];
            float t = (kind == 0) ? b2[ed] * gam[ed]
                    : (kind == 1) ? gam[ed]
                                  : bta[ed];
            acc = fmaf(t, w, acc);
        }
        acc += __shfl_xor(acc, 1);
        acc += __shfl_xor(acc, 2);
        if (qd == 0) ws[WS_D1K + (kind << 8) + (e2 << 4) + e] = acc;
    }
}

// ---------------------------------------------------------------------------
// Main kernel v4: 1024 blocks x 256 thr, 16 tokens/block (4/wave).
// LDS weight double-buffer via global_load_lds (issued before compute of the
// other buffer, m97-style); SINGLE register hidden buffer reloaded right
// after consumption (drained by the barrier's vmcnt(0)); no waves-per-EU
// hint (R3 showed it causes the backend to spill acc[] -> 215 MB scratch).
// ---------------------------------------------------------------------------
__global__ __launch_bounds__(256) void hr_main(
    const float* __restrict__ hidden, const float* __restrict__ wv,
    const float* __restrict__ wvb, const float* __restrict__ w1,
    const float* __restrict__ b1, const float* __restrict__ tab,
    float* __restrict__ out)
{
    __shared__ float lds[10240];   // 40960 B: wbuf[2][20][256]; aliased by epilogue

    const int tid  = threadIdx.x;
    const int wave = tid >> 6;
    const int lane = tid & 63;
    const int tok0 = (blockIdx.x << 4) + (wave << 2);
    const float* hb = hidden + (size_t)tok0 * INDIM + (lane << 2);

    float acc[NROWS][4];
    #pragma unroll
    for (int w = 0; w < NROWS; ++w) {
        acc[w][0] = 0.f; acc[w][1] = 0.f; acc[w][2] = 0.f; acc[w][3] = 0.f;
    }

    float4 ha[4];
    stage_rows(wv, w1, lds, wave, lane, 0);   // chunk 0 -> buf0
    load_h(ha, hb, 0);
    __syncthreads();                          // staging 0 + ha0 drained

    for (int cc = 0; cc < 4; ++cc) {
        const int c1 = 2 * cc + 1;
        stage_rows(wv, w1, lds + LBUF1, wave, lane, c1 << 8); // DMA odd -> buf1
        compute_chunk(acc, &lds[lane << 2], ha);              // compute even
        load_h(ha, hb, c1);                                   // reload ha (WAR ok)
        __syncthreads();                                      // drain buf1 DMA + ha
        if (cc != 3) stage_rows(wv, w1, lds, wave, lane, (c1 + 1) << 8);
        compute_chunk(acc, &lds[LBUF1 + (lane << 2)], ha);    // compute odd
        if (cc != 3) load_h(ha, hb, c1 + 1);
        __syncthreads();                                      // drain buf0 DMA + ha
    }

    // ---- reduction: 2 butterfly levels -> 16 partials per (w,t) ----
    #pragma unroll
    for (int w = 0; w < NROWS; ++w) {
        #pragma unroll
        for (int t = 0; t < 4; ++t) {
            float v = acc[w][t];
            v += __shfl_xor(v, 32);
            v += __shfl_xor(v, 16);
            acc[w][t] = v;     // lane l holds partial for i = l&15
        }
    }
    // scatter: quarter q = lane>>4 writes rows 5q..5q+4
    {
        const int q = lane >> 4, i = lane & 15;
        #pragma unroll
        for (int w = 0; w < NROWS; ++w) {
            if (q == w / 5) {
                #pragma unroll
                for (int t = 0; t < 4; ++t)
                    lds[((wave << 2) + t) * LRED2_STRIDE + (w << 4) + i] = acc[w][t];
            }
        }
    }
    __syncthreads();

    // gather: 320 (tok,w) pairs, sum 16 partials each -> red[tok][w]
    #pragma unroll
    for (int pp = 0; pp < 2; ++pp) {
        const int p = tid + pp * 256;
        if (p < 320) {
            const int w = p >> 4, tok = p & 15;
            const float4* rp = (const float4*)&lds[tok * LRED2_STRIDE + (w << 4)];
            float4 r0 = rp[0], r1 = rp[1], r2 = rp[2], r3 = rp[3];
            float s = (r0.x + r0.y + r0.z + r0.w) + (r1.x + r1.y + r1.z + r1.w)
                    + (r2.x + r2.y + r2.z + r2.w) + (r3.x + r3.y + r3.z + r3.w);
            lds[LRED + tok * 20 + w] = s;
        }
    }
    __syncthreads();

    // ---- tail: 16 threads per token, thread = (tok, e) ----
    const int tok = tid >> 4;
    const int e   = tid & 15;

    float ig[16];
    #pragma unroll
    for (int j = 0; j < 16; ++j) ig[j] = lds[LRED + tok * 20 + j] + wvb[j];
    float h[4];
    #pragma unroll
    for (int r = 0; r < 4; ++r) h[r] = fmaxf(lds[LRED + tok * 20 + 16 + r] + b1[r], 0.f);

    float muT = tab[WS_SCAL + 0];
    float e2m = tab[WS_SCAL + 1];
    #pragma unroll
    for (int r = 0; r < 4; ++r) {
        muT = fmaf(h[r], tab[WS_SCAL + 2 + r], muT);
        e2m = fmaf(2.f * h[r], tab[WS_SCAL + 6 + r], e2m);
        #pragma unroll
        for (int r2 = 0; r2 < 4; ++r2)
            e2m = fmaf(h[r] * h[r2], tab[WS_SCAL + 10 + r * 4 + r2], e2m);
    }
    const float var = e2m - muT * muT;
    const float rsq = rsqrtf(var + 1e-5f);

    float sv[16];
    #pragma unroll
    for (int e2 = 0; e2 < 16; ++e2) {
        float s = tab[WS_D1K + (e2 << 4) + e];
        s = fmaf(h[0], tab[(e2 << 6) + e], s);
        s = fmaf(h[1], tab[(e2 << 6) + 16 + e], s);
        s = fmaf(h[2], tab[(e2 << 6) + 32 + e], s);
        s = fmaf(h[3], tab[(e2 << 6) + 48 + e], s);
        s = fmaf(-muT, tab[WS_GQK + (e2 << 4) + e], s);
        sv[e2] = (rsq * s + tab[WS_BQK + (e2 << 4) + e]) * SIM_SCALE;
    }
    float mx = sv[0];
    #pragma unroll
    for (int e2 = 1; e2 < 16; ++e2) mx = fmaxf(mx, sv[e2]);
    float den = 0.f, gate = 0.f;
    #pragma unroll
    for (int e2 = 0; e2 < 16; ++e2) {
        float p = __expf(sv[e2] - mx);
        den += p;
        gate = fmaf(p, ig[e2], gate);
    }
    gate /= den;

    float gm = gate;
    gm = fmaxf(gm, __shfl_xor(gm, 1));
    gm = fmaxf(gm, __shfl_xor(gm, 2));
    gm = fmaxf(gm, __shfl_xor(gm, 4));
    gm = fmaxf(gm, __shfl_xor(gm, 8));
    float ex = __expf(gate - gm);
    float es = ex;
    es += __shfl_xor(es, 1);
    es += __shfl_xor(es, 2);
    es += __shfl_xor(es, 4);
    es += __shfl_xor(es, 8);
    const float rw = ex / es;

    float v1 = rw; int i1 = e;
    #pragma unroll
    for (int m = 1; m <= 8; m <<= 1) {
        float ov = __shfl_xor(v1, m);
        int   oi = __shfl_xor(i1, m);
        if (ov > v1 || (ov == v1 && oi < i1)) { v1 = ov; i1 = oi; }
    }
    float v2 = (e == i1) ? -INFINITY : rw; int i2 = e;
    #pragma unroll
    for (int m = 1; m <= 8; m <<= 1) {
        float ov = __shfl_xor(v2, m);
        int   oi = __shfl_xor(i2, m);
        if (ov > v2 || (ov == v2 && oi < i2)) { v2 = ov; i2 = oi; }
    }

    float oval = 0.f;
    if (e == i1 || e == i2) {
        float t = __expf((v2 - v1) * 10.f);
        oval = (e == i1) ? (1.f / (1.f + t)) : (t / (1.f + t));
    }
    out[(((size_t)blockIdx.x << 4) + tok) * 16 + e] = oval;
}

// ---------------------------------------------------------------------------
extern "C" void kernel_launch(void* const* d_in, const int* in_sizes, int n_in,
                              void* d_out, int out_size, void* d_ws, size_t ws_size,
                              hipStream_t stream)
{
    const float* hidden = (const float*)d_in[0];   // (4,4096,2048)
    const float* ee     = (const float*)d_in[1];   // (16,128)
    const float* gam    = (const float*)d_in[2];   // (16,128)
    const float* bta    = (const float*)d_in[3];   // (16,128)
    const float* wv     = (const float*)d_in[4];   // (16,2048)
    const float* wvb    = (const float*)d_in[5];   // (16,)
    const float* w1     = (const float*)d_in[6];   // (4,2048)
    const float* b1     = (const float*)d_in[7];   // (4,)
    const float* w2     = (const float*)d_in[8];   // (2048,4)
    const float* b2     = (const float*)d_in[9];   // (2048,)
    const float* wq     = (const float*)d_in[10];  // (128,128)
    const float* wk     = (const float*)d_in[11];  // (128,128)
    float* out = (float*)d_out;
    float* ws  = (float*)d_ws;

    hipLaunchKernelGGL(hr_pre2, dim3(17), dim3(256), 0, stream,
                       ee, gam, bta, w2, b2, wq, wk, ws);
    hipLaunchKernelGGL(hr_main, dim3(NTOK / 16), dim3(256), 0, stream,
                       hidden, wv, wvb, w1, b1, ws, out);
}

// Round 5
// 244.655 us; speedup vs baseline: 1.3733x; 1.0765x over previous
//
#include <hip/hip_runtime.h>
#include <math.h>

// Problem constants: B=4,S=4096,IN=2048,E=16,D=128,A=128,R=4
#define NTOK   16384
#define INDIM  2048
#define NROWS  20      // 16 Wv rows + 4 mlp_w1 rows
#define CHUNK  256     // K-chunk (floats): 1 KB per row, 8 chunks

// workspace (float) layout
#define WS_PKT  0      // PKt[e2][r][e]  : 16*4*16 = 1024
#define WS_D1K  1024   // [e2][e] 256
#define WS_GQK  1280   // [e2][e] 256
#define WS_BQK  1536   // [e2][e] 256
#define WS_SCAL 1792   // m0,q0,mW[4],q1[4],Q2[16] = 26
#define WS_TOT  1818

#define SIM_SCALE 0.08838834764831845f  // 1/sqrt(128)

// LDS float offsets inside hr_main's 73728-byte block
#define LBUF1   5120     // weight buffer 1           [5120,10240)
#define HBUF0   10240    // hidden buffer 0 16x256    [10240,14336)
#define HBUF1   14336    // hidden buffer 1           [14336,18432)
#define LRED2_STRIDE 324 // epilogue scatter stride (aliased over [0,5180))
#define LRED    5440     // red[16][20] epilogue buffer (aliased)

// ---------------------------------------------------------------------------
// async 16B global -> LDS (global_load_lds_dwordx4). HW uses lane0's LDS ptr
// as base and writes lane*16; we pass base + lane*16 so lane0 == row base.
// ---------------------------------------------------------------------------
__device__ __forceinline__ void async16(const float* g, float* l) {
    __builtin_amdgcn_global_load_lds(
        (const __attribute__((address_space(1))) void*)g,
        (__attribute__((address_space(3))) void*)l, 16, 0, 0);
}

// Stage one K-chunk: this wave's 5 weight rows (r = wave+4j) and its own 4
// token rows of hidden. 9 fire-and-forget DMAs; nothing lands in VGPRs.
__device__ __forceinline__ void stage_all(const float* __restrict__ wv,
                                          const float* __restrict__ w1,
                                          const float* __restrict__ hb_lane,
                                          float* ldsw, float* ldsh,
                                          int wave, int lane, int goff) {
    const int l4 = lane << 2;
    #pragma unroll
    for (int j = 0; j < 5; ++j) {
        const int r = wave + (j << 2);
        const float* src = (j < 4) ? (wv + (r << 11)) : (w1 + ((r - 16) << 11));
        async16(src + goff + l4, ldsw + r * CHUNK + l4);
    }
    #pragma unroll
    for (int t = 0; t < 4; ++t) {
        async16(hb_lane + t * INDIM + goff,
                ldsh + (((wave << 2) + t) * CHUNK) + l4);
    }
}

// K-loop body: 4 hidden ds_read_b128 + 20 weight ds_read_b128 + 320 FMA.
__device__ __forceinline__ void compute_chunk(float acc[NROWS][4],
                                              const float* wb,
                                              const float* hbl) {
    float4 h[4];
    #pragma unroll
    for (int t = 0; t < 4; ++t) h[t] = *(const float4*)(hbl + (t << 8));
    #pragma unroll
    for (int w = 0; w < NROWS; ++w) {
        float4 wf = *(const float4*)(wb + (w << 8));   // ds_read_b128
        #pragma unroll
        for (int t = 0; t < 4; ++t) {
            acc[w][t] = fmaf(h[t].x, wf.x,
                        fmaf(h[t].y, wf.y,
                        fmaf(h[t].z, wf.z,
                        fmaf(h[t].w, wf.w, acc[w][t]))));
        }
    }
}

// ---------------------------------------------------------------------------
// Precompute kernel: 17 blocks x 256 threads (unchanged, known-good).
// ---------------------------------------------------------------------------
__global__ __launch_bounds__(256) void hr_pre2(
    const float* __restrict__ ee, const float* __restrict__ gam,
    const float* __restrict__ bta, const float* __restrict__ w2,
    const float* __restrict__ b2, const float* __restrict__ wq,
    const float* __restrict__ wk, float* __restrict__ ws)
{
    const int tid  = threadIdx.x;
    const int bx   = blockIdx.x;
    const int lane = tid & 63;
    const int wave = tid >> 6;

    if (bx == 16) {
        __shared__ float sacc[26];
        if (tid < 26) sacc[tid] = 0.f;
        __syncthreads();
        float pa[26];
        #pragma unroll
        for (int j = 0; j < 26; ++j) pa[j] = 0.f;
        for (int i = tid; i < 2048; i += 256) {
            float b = b2[i];
            float4 w4 = *(const float4*)(w2 + i * 4);
            float wr[4] = {w4.x, w4.y, w4.z, w4.w};
            pa[0] += b;
            pa[1] += b * b;
            #pragma unroll
            for (int r = 0; r < 4; ++r) {
                pa[2 + r] += wr[r];
                pa[6 + r] += b * wr[r];
                #pragma unroll
                for (int r2 = 0; r2 < 4; ++r2) pa[10 + r * 4 + r2] += wr[r] * wr[r2];
            }
        }
        #pragma unroll
        for (int j = 0; j < 26; ++j) {
            float v = pa[j];
            v += __shfl_xor(v, 32); v += __shfl_xor(v, 16); v += __shfl_xor(v, 8);
            v += __shfl_xor(v, 4);  v += __shfl_xor(v, 2);  v += __shfl_xor(v, 1);
            if (lane == 0) atomicAdd(&sacc[j], v);
        }
        __syncthreads();
        if (tid < 26) ws[WS_SCAL + tid] = sacc[tid] * (1.f / 2048.f);
        return;
    }

    const int e2 = bx;
    __shared__ float sge[128];
    __shared__ float sK[128];
    __shared__ float sWqK[128];
    __shared__ float sred[8];

    float v8[8];
    float s = 0.f;
    #pragma unroll
    for (int j = 0; j < 8; ++j) { v8[j] = ee[tid + j * 256]; s += v8[j]; }
    s += __shfl_xor(s, 32); s += __shfl_xor(s, 16); s += __shfl_xor(s, 8);
    s += __shfl_xor(s, 4);  s += __shfl_xor(s, 2);  s += __shfl_xor(s, 1);
    if (lane == 0) sred[wave] = s;
    __syncthreads();
    const float mu = (sred[0] + sred[1] + sred[2] + sred[3]) * (1.f / 2048.f);
    float q = 0.f;
    #pragma unroll
    for (int j = 0; j < 8; ++j) { float d = v8[j] - mu; q += d * d; }
    q += __shfl_xor(q, 32); q += __shfl_xor(q, 16); q += __shfl_xor(q, 8);
    q += __shfl_xor(q, 4);  q += __shfl_xor(q, 2);  q += __shfl_xor(q, 1);
    if (lane == 0) sred[4 + wave] = q;
    __syncthreads();
    const float rsq = rsqrtf((sred[4] + sred[5] + sred[6] + sred[7]) * (1.f / 2048.f) + 1e-5f);

    if (tid < 128) {
        int idx = (e2 << 7) + tid;
        sge[tid] = (ee[idx] - mu) * rsq * gam[idx] + bta[idx];
    }
    __syncthreads();

    {
        int a = tid >> 1, half = tid & 1;
        const float* wr = wk + (a << 7) + (half << 6);
        const float* gg = sge + (half << 6);
        float acc = 0.f;
        #pragma unroll 8
        for (int j = 0; j < 64; ++j) acc = fmaf(gg[j], wr[j], acc);
        acc += __shfl_xor(acc, 1);
        if (half == 0) sK[a] = acc;
    }
    __syncthreads();

    {
        int d = tid >> 1, half = tid & 1;
        float acc = 0.f;
        #pragma unroll 8
        for (int j = 0; j < 64; ++j) {
            int a = (half << 6) + j;
            acc = fmaf(wq[(a << 7) + d], sK[a], acc);
        }
        acc += __shfl_xor(acc, 1);
        if (half == 0) sWqK[d] = acc;
    }
    __syncthreads();

    {
        int o = tid >> 2, qd = tid & 3;
        int r = o >> 4, e = o & 15;
        float acc = 0.f;
        #pragma unroll 8
        for (int j = 0; j < 32; ++j) {
            int d  = (qd << 5) + j;
            int ed = (e << 7) + d;
            acc = fmaf(w2[ed * 4 + r] * gam[ed], sWqK[d], acc);
        }
        acc += __shfl_xor(acc, 1);
        acc += __shfl_xor(acc, 2);
        if (qd == 0) ws[WS_PKT + (e2 << 6) + (r << 4) + e] = acc;
    }

    if (tid < 192) {
        int kind = tid >> 6;
        int e    = (tid >> 2) & 15;
        int qd   = tid & 3;
        float acc = 0.f;
        #pragma unroll 8
        for (int j = 0; j < 32; ++j) {
            int d  = (qd << 5) + j;
            int ed = (e << 7) + d;
            float w = sWqK[d];
            float t = (kind == 0) ? b2[ed] * gam[ed]
                    : (kind == 1) ? gam[ed]
                                  : bta[ed];
            acc = fmaf(t, w, acc);
        }
        acc += __shfl_xor(acc, 1);
        acc += __shfl_xor(acc, 2);
        if (qd == 0) ws[WS_D1K + (kind << 8) + (e2 << 4) + e] = acc;
    }
}

// ---------------------------------------------------------------------------
// Main kernel v5: 1024 blocks x 256 thr, 16 tokens/block (4/wave).
// BOTH weights and hidden staged via global_load_lds, double-buffered.
// All DMAs for chunk c+1 are issued BEFORE the compute of chunk c, so the
// barrier's vmcnt(0) drain waits only on ~1000-cycle-old DMAs — no freshly
// issued global load is ever pending at a barrier (R4's exposed-latency bug).
// K-loop has zero VGPR-bound global loads. No waves-per-EU hint (R3 spill).
// ---------------------------------------------------------------------------
__global__ __launch_bounds__(256) void hr_main(
    const float* __restrict__ hidden, const float* __restrict__ wv,
    const float* __restrict__ wvb, const float* __restrict__ w1,
    const float* __restrict__ b1, const float* __restrict__ tab,
    float* __restrict__ out)
{
    __shared__ float lds[18432];   // 73728 B: wbuf[2][20][256] + hbuf[2][16][256]

    const int tid  = threadIdx.x;
    const int wave = tid >> 6;
    const int lane = tid & 63;
    const int tok0 = (blockIdx.x << 4) + (wave << 2);
    // per-lane global src base for this wave's token 0
    const float* hb = hidden + (size_t)tok0 * INDIM + (lane << 2);

    float acc[NROWS][4];
    #pragma unroll
    for (int w = 0; w < NROWS; ++w) {
        acc[w][0] = 0.f; acc[w][1] = 0.f; acc[w][2] = 0.f; acc[w][3] = 0.f;
    }

    // per-lane LDS read pointers
    const float* wr0 = &lds[lane << 2];
    const float* wr1 = &lds[LBUF1 + (lane << 2)];
    const float* hr0 = &lds[HBUF0 + (wave << 10) + (lane << 2)];
    const float* hr1 = &lds[HBUF1 + (wave << 10) + (lane << 2)];

    stage_all(wv, w1, hb, lds, lds + HBUF0, wave, lane, 0);   // chunk 0 -> buf0
    __syncthreads();                                          // one-time cold drain

    for (int cc = 0; cc < 4; ++cc) {
        const int c1 = 2 * cc + 1;
        stage_all(wv, w1, hb, lds + LBUF1, lds + HBUF1, wave, lane, c1 << 8);
        compute_chunk(acc, wr0, hr0);                         // ~930 cyc cover
        __syncthreads();                                      // drains OLD buf1 DMAs
        if (cc != 3)
            stage_all(wv, w1, hb, lds, lds + HBUF0, wave, lane, (c1 + 1) << 8);
        compute_chunk(acc, wr1, hr1);
        __syncthreads();                                      // drains OLD buf0 DMAs
    }

    // ---- reduction: 2 butterfly levels -> 16 partials per (w,t) ----
    #pragma unroll
    for (int w = 0; w < NROWS; ++w) {
        #pragma unroll
        for (int t = 0; t < 4; ++t) {
            float v = acc[w][t];
            v += __shfl_xor(v, 32);
            v += __shfl_xor(v, 16);
            acc[w][t] = v;     // lane l holds partial for i = l&15
        }
    }
    // scatter: quarter q = lane>>4 writes rows 5q..5q+4 (aliases dead wbuf)
    {
        const int q = lane >> 4, i = lane & 15;
        #pragma unroll
        for (int w = 0; w < NROWS; ++w) {
            if (q == w / 5) {
                #pragma unroll
                for (int t = 0; t < 4; ++t)
                    lds[((wave << 2) + t) * LRED2_STRIDE + (w << 4) + i] = acc[w][t];
            }
        }
    }
    __syncthreads();

    // gather: 320 (tok,w) pairs, sum 16 partials each -> red[tok][w]
    #pragma unroll
    for (int pp = 0; pp < 2; ++pp) {
        const int p = tid + pp * 256;
        if (p < 320) {
            const int w = p >> 4, tok = p & 15;
            const float4* rp = (const float4*)&lds[tok * LRED2_STRIDE + (w << 4)];
            float4 r0 = rp[0], r1 = rp[1], r2 = rp[2], r3 = rp[3];
            float s = (r0.x + r0.y + r0.z + r0.w) + (r1.x + r1.y + r1.z + r1.w)
                    + (r2.x + r2.y + r2.z + r2.w) + (r3.x + r3.y + r3.z + r3.w);
            lds[LRED + tok * 20 + w] = s;
        }
    }
    __syncthreads();

    // ---- tail: 16 threads per token, thread = (tok, e) ----
    const int tok = tid >> 4;
    const int e   = tid & 15;

    float ig[16];
    #pragma unroll
    for (int j = 0; j < 16; ++j) ig[j] = lds[LRED + tok * 20 + j] + wvb[j];
    float h[4];
    #pragma unroll
    for (int r = 0; r < 4; ++r) h[r] = fmaxf(lds[LRED + tok * 20 + 16 + r] + b1[r], 0.f);

    float muT = tab[WS_SCAL + 0];
    float e2m = tab[WS_SCAL + 1];
    #pragma unroll
    for (int r = 0; r < 4; ++r) {
        muT = fmaf(h[r], tab[WS_SCAL + 2 + r], muT);
        e2m = fmaf(2.f * h[r], tab[WS_SCAL + 6 + r], e2m);
        #pragma unroll
        for (int r2 = 0; r2 < 4; ++r2)
            e2m = fmaf(h[r] * h[r2], tab[WS_SCAL + 10 + r * 4 + r2], e2m);
    }
    const float var = e2m - muT * muT;
    const float rsq = rsqrtf(var + 1e-5f);

    float sv[16];
    #pragma unroll
    for (int e2 = 0; e2 < 16; ++e2) {
        float s = tab[WS_D1K + (e2 << 4) + e];
        s = fmaf(h[0], tab[(e2 << 6) + e], s);
        s = fmaf(h[1], tab[(e2 << 6) + 16 + e], s);
        s = fmaf(h[2], tab[(e2 << 6) + 32 + e], s);
        s = fmaf(h[3], tab[(e2 << 6) + 48 + e], s);
        s = fmaf(-muT, tab[WS_GQK + (e2 << 4) + e], s);
        sv[e2] = (rsq * s + tab[WS_BQK + (e2 << 4) + e]) * SIM_SCALE;
    }
    float mx = sv[0];
    #pragma unroll
    for (int e2 = 1; e2 < 16; ++e2) mx = fmaxf(mx, sv[e2]);
    float den = 0.f, gate = 0.f;
    #pragma unroll
    for (int e2 = 0; e2 < 16; ++e2) {
        float p = __expf(sv[e2] - mx);
        den += p;
        gate = fmaf(p, ig[e2], gate);
    }
    gate /= den;

    float gm = gate;
    gm = fmaxf(gm, __shfl_xor(gm, 1));
    gm = fmaxf(gm, __shfl_xor(gm, 2));
    gm = fmaxf(gm, __shfl_xor(gm, 4));
    gm = fmaxf(gm, __shfl_xor(gm, 8));
    float ex = __expf(gate - gm);
    float es = ex;
    es += __shfl_xor(es, 1);
    es += __shfl_xor(es, 2);
    es += __shfl_xor(es, 4);
    es += __shfl_xor(es, 8);
    const float rw = ex / es;

    float v1 = rw; int i1 = e;
    #pragma unroll
    for (int m = 1; m <= 8; m <<= 1) {
        float ov = __shfl_xor(v1, m);
        int   oi = __shfl_xor(i1, m);
        if (ov > v1 || (ov == v1 && oi < i1)) { v1 = ov; i1 = oi; }
    }
    float v2 = (e == i1) ? -INFINITY : rw; int i2 = e;
    #pragma unroll
    for (int m = 1; m <= 8; m <<= 1) {
        float ov = __shfl_xor(v2, m);
        int   oi = __shfl_xor(i2, m);
        if (ov > v2 || (ov == v2 && oi < i2)) { v2 = ov; i2 = oi; }
    }

    float oval = 0.f;
    if (e == i1 || e == i2) {
        float t = __expf((v2 - v1) * 10.f);
        oval = (e == i1) ? (1.f / (1.f + t)) : (t / (1.f + t));
    }
    out[(((size_t)blockIdx.x << 4) + tok) * 16 + e] = oval;
}

// ---------------------------------------------------------------------------
extern "C" void kernel_launch(void* const* d_in, const int* in_sizes, int n_in,
                              void* d_out, int out_size, void* d_ws, size_t ws_size,
                              hipStream_t stream)
{
    const float* hidden = (const float*)d_in[0];   // (4,4096,2048)
    const float* ee     = (const float*)d_in[1];   // (16,128)
    const float* gam    = (const float*)d_in[2];   // (16,128)
    const float* bta    = (const float*)d_in[3];   // (16,128)
    const float* wv     = (const float*)d_in[4];   // (16,2048)
    const float* wvb    = (const float*)d_in[5];   // (16,)
    const float* w1     = (const float*)d_in[6];   // (4,2048)
    const float* b1     = (const float*)d_in[7];   // (4,)
    const float* w2     = (const float*)d_in[8];   // (2048,4)
    const float* b2     = (const float*)d_in[9];   // (2048,)
    const float* wq     = (const float*)d_in[10];  // (128,128)
    const float* wk     = (const float*)d_in[11];  // (128,128)
    float* out = (float*)d_out;
    float* ws  = (float*)d_ws;

    hipLaunchKernelGGL(hr_pre2, dim3(17), dim3(256), 0, stream,
                       ee, gam, bta, w2, b2, wq, wk, ws);
    hipLaunchKernelGGL(hr_main, dim3(NTOK / 16), dim3(256), 0, stream,
                       hidden, wv, wvb, w1, b1, ws, out);
}